// Round 1
// 582.804 us; speedup vs baseline: 1.0727x; 1.0727x over previous
//
#include <hip/hip_runtime.h>

// ---------------- problem constants ----------------
#define M_DIM 2048        // tlen*batch
#define K_DIM 1024        // input_size
#define N_DIM 32000       // vocab
#define CVOCAB 120
#define AGENDA 100
#define SLEN 400
#define CTX 300
#define BATCH 16
#define OUT_STRIDE 32120  // vocab + cvocab
#define PAD_IDX 1

#define TM 256            // GEMM tile M
#define TN 256            // GEMM tile N
#define BK 64             // GEMM K-step
#define BUFSZ (TM * BK)   // ushorts per LDS tile buffer (32 KB)
#define NKT (K_DIM / BK)  // 16
#define MT (M_DIM / TM)   // 8
#define NT (N_DIM / TN)   // 125

typedef float f32x4_t  __attribute__((ext_vector_type(4)));
typedef __bf16 bf16x8_t __attribute__((ext_vector_type(8)));
typedef unsigned short u16x8_t __attribute__((ext_vector_type(8)));
typedef unsigned short u16x4_t __attribute__((ext_vector_type(4)));

// RNE fp32 -> bf16 (values are all normal, no NaN handling needed)
__device__ __forceinline__ unsigned short f2bf(float f) {
    union { float f; unsigned int u; } c; c.f = f;
    unsigned int u = c.u;
    u += 0x7FFFu + ((u >> 16) & 1u);
    return (unsigned short)(u >> 16);
}

// fp32 <-> fp16 (exp values in [0, ~60]: fp16-safe, 2^-11 rel err << tolerance)
__device__ __forceinline__ unsigned short f2h(float f) {
    _Float16 h = (_Float16)f;
    unsigned short u; __builtin_memcpy(&u, &h, 2); return u;
}
__device__ __forceinline__ float h2f(unsigned short u) {
    _Float16 h; __builtin_memcpy(&h, &u, 2); return (float)h;
}

// async 16B global->LDS (dest = wave-uniform base + lane*16)
__device__ __forceinline__ void async_copy16(const void* gsrc, void* ldst) {
    __builtin_amdgcn_global_load_lds(
        (__attribute__((address_space(1))) unsigned int*)(gsrc),
        (__attribute__((address_space(3))) unsigned int*)(ldst),
        16, 0, 0);
}

// ---------------- kernel 1: fp32 -> bf16 cast of W and hidden ----------------
__global__ void cast_bf16_kernel(const float4* __restrict__ W, const float4* __restrict__ H,
                                 unsigned short* __restrict__ Wb, unsigned short* __restrict__ Hb) {
    const size_t NW4 = (size_t)N_DIM * K_DIM / 4;   // 8,192,000
    const size_t NH4 = (size_t)M_DIM * K_DIM / 4;   // 524,288
    size_t idx = (size_t)blockIdx.x * 256 + threadIdx.x;
    float4 v; unsigned short* dst;
    if (idx < NW4)            { v = W[idx];        dst = Wb + idx * 4; }
    else if (idx < NW4 + NH4) { v = H[idx - NW4];  dst = Hb + (idx - NW4) * 4; }
    else return;
    u16x4_t o;
    o[0] = f2bf(v.x); o[1] = f2bf(v.y); o[2] = f2bf(v.z); o[3] = f2bf(v.w);
    *(u16x4_t*)dst = o;
}

// ---------------- kernel 2: p_copy = sigmoid(hidden @ W_copy^T + b_copy) ----------------
// Also zeroes rowsum (runs before GEMM) so the memset dispatch goes away.
__global__ void pcopy_kernel(const float* __restrict__ hidden, const float* __restrict__ Wc,
                             const float* __restrict__ bc, float* __restrict__ pcopy,
                             float* __restrict__ rowsum) {
    int row  = blockIdx.x * 4 + (threadIdx.x >> 6);  // 4 waves/block, 1 row/wave
    int lane = threadIdx.x & 63;
    const float4* h = (const float4*)(hidden + (size_t)row * K_DIM);
    const float4* w = (const float4*)Wc;
    float s = 0.f;
    #pragma unroll
    for (int i = 0; i < 4; ++i) {
        float4 a = h[lane + 64 * i];
        float4 b = w[lane + 64 * i];
        s += a.x * b.x + a.y * b.y + a.z * b.z + a.w * b.w;
    }
    #pragma unroll
    for (int m = 1; m < 64; m <<= 1) s += __shfl_xor(s, m);
    if (lane == 0) {
        float p = 1.0f / (1.0f + __expf(-(s + bc[0])));
        pcopy[row] = p;
        rowsum[row] = 0.0f;
    }
}

// ---------------- kernel 3: GEMM + exp + row-sum (256x256 tile, 16 waves) ----------------
// Double-buffered LDS (minimal 2-phase pipeline: stage k+1 before computing k,
// single vmcnt(0)+barrier per K-step). XCD-aware tile swizzle. Writes exp as
// fp16 IN-PLACE into the first 64000 bytes of each out row (finalize expands).
__global__ __launch_bounds__(1024, 4) void gemm_exp_kernel(
    const unsigned short* __restrict__ A,   // M x K bf16
    const unsigned short* __restrict__ B,   // N x K bf16
    const float* __restrict__ bias,         // N
    float* __restrict__ out,                // row stride OUT_STRIDE (fp16 staging area)
    float* __restrict__ rowsum)             // M (zeroed by pcopy_kernel)
{
    __shared__ unsigned short sA[2][BUFSZ]; // 64 KB
    __shared__ unsigned short sB[2][BUFSZ]; // 64 KB
    __shared__ float sRow[TM];              // 1 KB   (total 129 KB -> 1 block/CU)

    const int tid   = threadIdx.x;          // 0..1023
    const int lane  = tid & 63;
    const int q     = lane >> 4;
    const int lr    = lane & 15;
    const int wv    = tid >> 6;             // 0..15
    const int waveM = wv >> 2;              // 0..3 -> 64-row quarter
    const int waveN = wv & 3;               // 0..3 -> 64-col quarter

    // XCD swizzle: hardware round-robins bid%8 across the 8 XCDs. Map so each
    // XCD walks its own contiguous range of tiles M-fastest: the 8 M-tiles of
    // one B-panel run back-to-back on one XCD -> panel is an L2 hit 7/8 times,
    // and each panel is HBM-fetched by ~1 XCD instead of all 8.
    const int bid = blockIdx.x;
    const int t   = (bid & 7) * NT + (bid >> 3);   // 1000 = 8*125: bijective
    const int rowBase = (t & 7) * TM;
    const int colBase = (t >> 3) * TN;

    f32x4_t acc[4][4] = {};
    if (tid < TM) sRow[tid] = 0.0f;

    // Staging: tile = 256 rows x 64 k (128B/row = 8 chunks of 16B) = 2048 chunks, 2/thread.
    // LDS chunk slot s holds source chunk s ^ (row&7)  (XOR swizzle: conflict-free reads)
    const int p0 = tid,        m0 = p0 >> 3, j0 = (p0 & 7) ^ (m0 & 7);
    const int p1 = 1024 + tid, m1 = p1 >> 3, j1 = (p1 & 7) ^ (m1 & 7);
    const unsigned short* aSrc0 = A + (size_t)(rowBase + m0) * K_DIM + j0 * 8;
    const unsigned short* aSrc1 = A + (size_t)(rowBase + m1) * K_DIM + j1 * 8;
    const unsigned short* bSrc0 = B + (size_t)(colBase + m0) * K_DIM + j0 * 8;
    const unsigned short* bSrc1 = B + (size_t)(colBase + m1) * K_DIM + j1 * 8;
    const int dOff0 = (tid & ~63) * 8;
    const int dOff1 = (1024 + (tid & ~63)) * 8;

    // prologue: stage tile 0 into buffer 0 (syncthreads drains vmcnt)
    async_copy16(aSrc0, &sA[0][dOff0]);
    async_copy16(aSrc1, &sA[0][dOff1]);
    async_copy16(bSrc0, &sB[0][dOff0]);
    async_copy16(bSrc1, &sB[0][dOff1]);
    __syncthreads();

    for (int kt = 0; kt < NKT; ++kt) {
        const int cur = kt & 1;
        if (kt + 1 < NKT) {       // issue next tile's loads BEFORE computing this one
            const int nb = cur ^ 1;
            const int k0 = (kt + 1) * BK;
            async_copy16(aSrc0 + k0, &sA[nb][dOff0]);
            async_copy16(aSrc1 + k0, &sA[nb][dOff1]);
            async_copy16(bSrc0 + k0, &sB[nb][dOff0]);
            async_copy16(bSrc1 + k0, &sB[nb][dOff1]);
        }
        const unsigned short* pA = sA[cur];
        const unsigned short* pB = sB[cur];
        #pragma unroll
        for (int s = 0; s < 2; ++s) {   // two 16x16x32 K-steps
            u16x8_t af[4], bfr[4];
            #pragma unroll
            for (int r = 0; r < 4; ++r) {
                int m  = waveM * 64 + r * 16 + lr;
                int ch = (s * 4 + q) ^ (m & 7);
                af[r] = *(const u16x8_t*)(pA + m * BK + ch * 8);
            }
            #pragma unroll
            for (int c = 0; c < 4; ++c) {
                int n  = waveN * 64 + c * 16 + lr;
                int ch = (s * 4 + q) ^ (n & 7);
                bfr[c] = *(const u16x8_t*)(pB + n * BK + ch * 8);
            }
            #pragma unroll
            for (int r = 0; r < 4; ++r)
                #pragma unroll
                for (int c = 0; c < 4; ++c)
                    acc[r][c] = __builtin_amdgcn_mfma_f32_16x16x32_bf16(
                        __builtin_bit_cast(bf16x8_t, af[r]),
                        __builtin_bit_cast(bf16x8_t, bfr[c]),
                        acc[r][c], 0, 0, 0);
        }
        __syncthreads();  // drains this iter's prefetch (vmcnt 0) + read-protects buffers
    }

    // epilogue: C/D layout col=lane&15 (vocab n), row=quad*4+reg (token m)
    float bb[4];
    #pragma unroll
    for (int c = 0; c < 4; ++c) bb[c] = bias[colBase + waveN * 64 + c * 16 + lr];

    #pragma unroll
    for (int r = 0; r < 4; ++r) {
        float rsum[4] = {0.f, 0.f, 0.f, 0.f};
        #pragma unroll
        for (int c = 0; c < 4; ++c) {
            int gcol = colBase + waveN * 64 + c * 16 + lr;
            bool pad = (gcol == PAD_IDX);
            #pragma unroll
            for (int d = 0; d < 4; ++d) {
                int grow = rowBase + waveM * 64 + r * 16 + q * 4 + d;
                float e = pad ? 0.0f : __expf(acc[r][c][d] + bb[c]);
                // fp16 in-place: first 64000 B of the row's fp32 region
                ((unsigned short*)(out + (size_t)grow * OUT_STRIDE))[gcol] = f2h(e);
                rsum[d] += e;
            }
        }
        #pragma unroll
        for (int d = 0; d < 4; ++d) {
            float v = rsum[d];
            v += __shfl_xor(v, 1);
            v += __shfl_xor(v, 2);
            v += __shfl_xor(v, 4);
            v += __shfl_xor(v, 8);
            if (lr == 0) {
                int lrow = waveM * 64 + r * 16 + q * 4 + d;
                atomicAdd(&sRow[lrow], v);   // LDS atomic: 4x fewer global atomics
            }
        }
    }
    __syncthreads();
    if (tid < TM) atomicAdd(&rowsum[rowBase + tid], sRow[tid]);
}

// ---------------- kernel 4: fused normalize + copy_prob + p_copy tail ----------------
// Reads the row's fp16 exp values (64 KB) into LDS, then expands to normalized
// fp32 in place. Halves the finalize read traffic and GEMM's write traffic.
__global__ __launch_bounds__(512) void finalize_kernel(
    float* __restrict__ out, const float* __restrict__ rowsum,
    const float* __restrict__ pcopy, const float* __restrict__ attn,
    const float* __restrict__ src_map, float* __restrict__ out_tail) {
    const int n   = blockIdx.x;        // row (t*BATCH + b)
    const int tid = threadIdx.x;       // 512 threads
    __shared__ unsigned short sE[N_DIM];   // 64000 B
    __shared__ float ma[AGENDA];

    const float p = pcopy[n];
    const float scale = (1.0f - p) / rowsum[n];

    // stage fp16 row into LDS before any fp32 write clobbers it
    const u16x8_t* src = (const u16x8_t*)(out + (size_t)n * OUT_STRIDE);
    for (int j = tid; j < N_DIM / 8; j += 512)
        *(u16x8_t*)(sE + j * 8) = src[j];
    if (tid < AGENDA) ma[tid] = attn[(size_t)n * SLEN + CTX + tid] * p;
    __syncthreads();

    float4* row4 = (float4*)(out + (size_t)n * OUT_STRIDE);
    for (int j = tid; j < N_DIM / 4; j += 512) {
        u16x4_t h = *(const u16x4_t*)(sE + j * 4);
        float4 v;
        v.x = h2f(h[0]) * scale;
        v.y = h2f(h[1]) * scale;
        v.z = h2f(h[2]) * scale;
        v.w = h2f(h[3]) * scale;
        row4[j] = v;
    }

    if (tid < CVOCAB) {
        int bidx = n & (BATCH - 1);
        float s = 0.f;
        #pragma unroll 4
        for (int a = 0; a < AGENDA; ++a)
            s += ma[a] * src_map[(size_t)(a * BATCH + bidx) * CVOCAB + tid];
        out[(size_t)n * OUT_STRIDE + N_DIM + tid] = s;
    }
    if (tid == 0) out_tail[n] = p;
}

// ---------------- launch ----------------
extern "C" void kernel_launch(void* const* d_in, const int* in_sizes, int n_in,
                              void* d_out, int out_size, void* d_ws, size_t ws_size,
                              hipStream_t stream) {
    const float* hidden  = (const float*)d_in[0];
    const float* attn    = (const float*)d_in[1];
    const float* src_map = (const float*)d_in[2];
    const float* W       = (const float*)d_in[3];
    const float* b       = (const float*)d_in[4];
    const float* W_copy  = (const float*)d_in[5];
    const float* b_copy  = (const float*)d_in[6];
    float* out = (float*)d_out;

    // workspace layout (unchanged, ~70 MB)
    char* ws = (char*)d_ws;
    unsigned short* Wb = (unsigned short*)ws;                               // 65,536,000 B
    unsigned short* Hb = (unsigned short*)(ws + 65536000);                  //  4,194,304 B
    float* rowsum      = (float*)(ws + 65536000 + 4194304);                 //      8,192 B
    float* pcopy       = (float*)(ws + 65536000 + 4194304 + 8192);          //      8,192 B

    float* out_tail = out + (size_t)M_DIM * OUT_STRIDE;  // p_copy output

    // 1. cast W + hidden to bf16
    {
        size_t total4 = (size_t)N_DIM * K_DIM / 4 + (size_t)M_DIM * K_DIM / 4;
        int blocks = (int)((total4 + 255) / 256);
        cast_bf16_kernel<<<blocks, 256, 0, stream>>>((const float4*)W, (const float4*)hidden, Wb, Hb);
    }
    // 2. p_copy (also zeroes rowsum — ws is poisoned every call)
    pcopy_kernel<<<M_DIM / 4, 256, 0, stream>>>(hidden, W_copy, b_copy, pcopy, rowsum);
    // 3. GEMM + exp + rowsum  (1D grid, XCD-swizzled tile decomposition inside)
    gemm_exp_kernel<<<MT * NT, 1024, 0, stream>>>(Hb, Wb, b, out, rowsum);
    // 4. fused normalize + copy_prob + p_copy tail
    finalize_kernel<<<M_DIM, 512, 0, stream>>>(out, rowsum, pcopy, attn, src_map, out_tail);
}